// Round 11
// baseline (241.906 us; speedup 1.0000x reference)
//
#include <hip/hip_runtime.h>
#include <hip/hip_bf16.h>

#define N_NODES 10000
#define N_EDGES 30000
#define F_NODE  32
#define F_EDGE  8
#define EMB     64
#define HID     16
#define NGRAPH  64
#define NBUCK   625              // 10000/16 exact
#define CAP     128              // slots per bucket (mean 48; src verified r6-r10, dst same dist)
#define ROWW    514              // U_lds row stride in words (514%32=2 -> bank spread; r7-verified)

typedef __attribute__((ext_vector_type(8))) short short8;   // 8 bf16 (MFMA A/B frag)
typedef __attribute__((ext_vector_type(4))) float f32x4;    // MFMA C/D frag

__device__ __forceinline__ unsigned short f2b(float f) {
    __hip_bfloat16 h = __float2bfloat16(f);
    return __builtin_bit_cast(unsigned short, h);
}

struct P {
    const float *x_p, *ea;
    const int *src, *dst, *batch;
    const float *nn0_w1, *nn0_b1, *nn0_w2, *nn0_b2;
    const float *nn1_w1, *nn1_b1, *nn1_w2, *nn1_b2;
    const float *root0, *bias0, *root1, *bias1, *root2, *bias2;
    const float *lin0_w, *lin0_b, *lin1_w, *lin1_b;
    float *out;
    int *cnt, *dcnt, *metap, *dstm;
    float *A1p;
    float *MSGa, *MSGb, *X0, *X1, *POOL;
};

// ---------------------------------------------------------------------------
// Fused conv kernel, 512 threads (8 waves), block b owns nodes [16b,16b+16).
//   CONV==0: zero POOL (blocks 0-1); scan src AND dst (int4, L2-resident) ->
//     LDS lists; dst-list+counts -> global for later gathers; edge-MLP for
//     own src edges (a0 -> LDS, a1 -> global).
//   CONV>0 prologue: gather own rows' incoming messages from MSGin via
//     dst-list + LDS ds_add (NO global atomics), then X = relu(gather +
//     x_prev@root + bias) -> Xt + global X0/X1.
//   MFMA: U tile -> LDS; B-fragments converted f32->bf16 ON THE FLY from the
//     original weights (16-lane o-groups read consecutive floats ->
//     coalesced; weights L2-resident). U layout word = row*514+(h>>1)*64+o:
//     conflict-free writes/reads (r7: 4.9M conflicts -> 0).
//   Edge loop: msg = XB + sum_h A*U -> PLAIN coalesced store MSGout[e][o].
// MSG ping-pong: conv0->MSGa, conv1: in MSGa out MSGb, conv2: in MSGb out
// MSGa (prologue reads and edge stores never share a buffer in-dispatch).
// No global atomics anywhere in this kernel; no cross-block sync.
// ---------------------------------------------------------------------------
template <int CONV>
__global__ void __launch_bounds__(512) k_fused(P p) {
    constexpr int K = (CONV == 0) ? F_NODE : EMB;
    __shared__ unsigned short U2[16 * 2 * ROWW];   // 32.9 KB
    __shared__ float XB_l[16][65];
    __shared__ float Xt[16][65];                   // CONV>0 only (DCE'd in f0)
    __shared__ float A0l[CAP][HID];                // CONV==0 only
    __shared__ int lds_e[CAP];                     // CONV==0: src list (e<<4|sloc)
    __shared__ int lds_d[CAP];                     // CONV==0: dst list (e<<4|dloc)
    __shared__ int lcs, lcd;
    const int b = blockIdx.x, t = threadIdx.x;
    const int n0 = b * 16;
    const int w = t >> 6, l = t & 63;
    const int lrow = l & 15, lk4 = l >> 4;
    int scnt = 0;

    if (CONV == 0) {
        int gtid = b * 512 + t;                    // POOL zero: blocks 0-1
        if (gtid < (NGRAPH * EMB) / 4)
            ((float4*)p.POOL)[gtid] = float4{0.f, 0.f, 0.f, 0.f};
        if (t == 0) { lcs = 0; lcd = 0; }
        __syncthreads();
        const int4* s4 = (const int4*)p.src;
        const int4* d4 = (const int4*)p.dst;
        for (int i = t; i < N_EDGES / 4; i += 512) {
            int4 sv = s4[i];
            int4 dv = d4[i];
            int e0 = i * 4;
#define CHK(sx, dx, eo)                                                                           \
            if (((sx) >> 4) == b) { int sl = atomicAdd(&lcs, 1); if (sl < CAP) lds_e[sl] = (((e0) + (eo)) << 4) | ((sx) & 15); } \
            if (((dx) >> 4) == b) { int sl = atomicAdd(&lcd, 1); if (sl < CAP) lds_d[sl] = (((e0) + (eo)) << 4) | ((dx) & 15); }
            CHK(sv.x, dv.x, 0) CHK(sv.y, dv.y, 1) CHK(sv.z, dv.z, 2) CHK(sv.w, dv.w, 3)
#undef CHK
        }
        __syncthreads();
        scnt = lcs; if (scnt > CAP) scnt = CAP;
        int dcv = lcd; if (dcv > CAP) dcv = CAP;
        if (t == 0) { p.cnt[b] = scnt; p.dcnt[b] = dcv; }
        if (t < dcv) p.dstm[(size_t)b * CAP + t] = lds_d[t];
        // edge-MLP for own src edges (first scnt threads; ~48 typical)
        if (t < scnt) {
            int pk = lds_e[t];
            int e = pk >> 4;
            p.metap[(size_t)b * CAP + t] = pk;
            const float4* ea4 = (const float4*)(p.ea + (size_t)e * F_EDGE);
            float4 ef0 = ea4[0], ef1 = ea4[1];
            float fv[F_EDGE] = {ef0.x, ef0.y, ef0.z, ef0.w, ef1.x, ef1.y, ef1.z, ef1.w};
            float a1v[HID];
#pragma unroll
            for (int h = 0; h < HID; h++) {
                float s0 = p.nn0_b1[h], s1 = p.nn1_b1[h];
#pragma unroll
                for (int i = 0; i < F_EDGE; i++) {
                    s0 += fv[i] * p.nn0_w1[i * HID + h];
                    s1 += fv[i] * p.nn1_w1[i * HID + h];
                }
                A0l[t][h] = fmaxf(s0, 0.f);
                a1v[h] = fmaxf(s1, 0.f);
            }
            float4* A1g = (float4*)(p.A1p + ((size_t)b * CAP + t) * HID);
#pragma unroll
            for (int j = 0; j < 4; j++)
                A1g[j] = float4{a1v[4 * j], a1v[4 * j + 1], a1v[4 * j + 2], a1v[4 * j + 3]};
        }
        // A0l/lds_e visibility covered by the post-MFMA __syncthreads
    }

    if (CONV > 0) {
        // prologue 1: gather incoming messages for own rows (LDS ds_add only)
        int dcv = p.dcnt[b];
        for (int idx = t; idx < 16 * 64; idx += 512) Xt[idx >> 6][idx & 63] = 0.f;
        __syncthreads();
        const float* MSGin = (CONV == 1) ? p.MSGa : p.MSGb;
        for (int jj = w; jj < dcv; jj += 8) {
            int q = __builtin_amdgcn_readfirstlane(jj);
            int mt = p.dstm[(size_t)b * CAP + q];      // s_load (q uniform)
            int e = mt >> 4, dloc = mt & 15;
            atomicAdd(&Xt[dloc][l], MSGin[(size_t)e * EMB + l]);   // ds_add_f32
        }
        __syncthreads();
        // prologue 2: node update X = relu(gather + x_prev@root + bias)
        const float* rt = (CONV == 1) ? p.root0 : p.root1;
        const float* bs = (CONV == 1) ? p.bias0 : p.bias1;
        constexpr int IN = (CONV == 1) ? F_NODE : EMB;
        for (int idx = t; idx < 16 * 64; idx += 512) {
            int j = idx >> 6, o = idx & 63;
            int n = n0 + j;
            float s = Xt[j][o] + bs[o];
            const float* xr = (CONV == 1) ? (p.x_p + (size_t)n * IN)
                                          : (p.X0 + (size_t)n * IN);
#pragma unroll
            for (int i = 0; i < IN; i++) s += xr[i] * rt[i * EMB + o];
            float sv = fmaxf(s, 0.f);
            Xt[j][o] = sv;
            if (CONV == 1) p.X0[n * EMB + o] = sv;
            else           p.X1[n * EMB + o] = sv;
        }
        __syncthreads();
        scnt = p.cnt[b];
    }

    // ---- MFMA: C[16 x 1088] = X_tile @ W^T, B-fragments on the fly
    short8 afr[K / 32];
    if (CONV == 0) {
        const float* xp = p.x_p + (size_t)(n0 + lrow) * F_NODE + lk4 * 8;
#pragma unroll
        for (int q = 0; q < 8; q++) afr[0][q] = (short)f2b(xp[q]);
    } else {
#pragma unroll
        for (int kk = 0; kk < K / 32; kk++)
#pragma unroll
            for (int q = 0; q < 8; q++)
                afr[kk][q] = (short)f2b(Xt[lrow][kk * 32 + lk4 * 8 + q]);
    }
    for (int i = 0; i <= 8; i++) {
        int T = w + 8 * i;
        if (T >= 68) break;
        short8 bfr[K / 32];
        if (T < 64) {
            int h = T & 15, ob = ((T >> 4) << 4) + lrow;
            const float* wb = (CONV == 0) ? (p.nn0_w2 + (size_t)h * (F_NODE * EMB) + ob)
                                          : (p.nn1_w2 + (size_t)h * (EMB * EMB) + ob);
#pragma unroll
            for (int kk = 0; kk < K / 32; kk++)
#pragma unroll
                for (int q = 0; q < 8; q++)
                    bfr[kk][q] = (short)f2b(wb[(size_t)(kk * 32 + lk4 * 8 + q) * EMB]);
        } else {
            int col = (T - 64) * 16 + lrow;
            const float* bb = (CONV == 0) ? (p.nn0_b2 + col) : (p.nn1_b2 + col);
#pragma unroll
            for (int kk = 0; kk < K / 32; kk++)
#pragma unroll
                for (int q = 0; q < 8; q++)
                    bfr[kk][q] = (short)f2b(bb[(size_t)(kk * 32 + lk4 * 8 + q) * EMB]);
        }
        f32x4 acc = {0.f, 0.f, 0.f, 0.f};
#pragma unroll
        for (int kk = 0; kk < K / 32; kk++)
            acc = __builtin_amdgcn_mfma_f32_16x16x32_bf16(afr[kk], bfr[kk], acc, 0, 0, 0);
        if (T < 64) {
            int h = T & 15, hw = h >> 1, hb = h & 1;
            int ob = ((T >> 4) << 4) + lrow;          // this lane's o
#pragma unroll
            for (int r = 0; r < 4; r++)
                U2[(lk4 * 4 + r) * (2 * ROWW) + hw * 128 + ob * 2 + hb] = f2b(acc[r]);
        } else {
            int col = (T - 64) * 16 + lrow;
#pragma unroll
            for (int r = 0; r < 4; r++)
                XB_l[lk4 * 4 + r][col] = acc[r];
        }
    }
    __syncthreads();

    // ---- edge loop over this block's src-bucket -> PLAIN stores to MSGout
    float* MSGout = (CONV == 1) ? p.MSGb : p.MSGa;
    const size_t base = (size_t)b * CAP;
    const int o = l;
#pragma unroll 2
    for (int qi = w; qi < scnt; qi += 8) {
        int q = __builtin_amdgcn_readfirstlane(qi);
        int mt;
        float av[HID];
        if (CONV == 0) {
            mt = lds_e[q];
            const float4* a4 = (const float4*)A0l[q];     // LDS broadcast b128
            float4 u0 = a4[0], u1 = a4[1], u2 = a4[2], u3 = a4[3];
            av[0]=u0.x; av[1]=u0.y; av[2]=u0.z; av[3]=u0.w;
            av[4]=u1.x; av[5]=u1.y; av[6]=u1.z; av[7]=u1.w;
            av[8]=u2.x; av[9]=u2.y; av[10]=u2.z; av[11]=u2.w;
            av[12]=u3.x; av[13]=u3.y; av[14]=u3.z; av[15]=u3.w;
        } else {
            mt = p.metap[base + q];                       // s_load (q uniform)
            const float* Ae = p.A1p + (base + q) * HID;   // contiguous s_loads
#pragma unroll
            for (int h = 0; h < HID; h++) av[h] = Ae[h];
        }
        int e = mt >> 4, sloc = mt & 15;
        const unsigned* up = reinterpret_cast<const unsigned*>(U2) + sloc * ROWW + o;
        float m = XB_l[sloc][o];
#define ACC2(wrd, h)                                                              \
        m = fmaf(__builtin_bit_cast(float, (unsigned)(wrd) << 16), av[h], m);     \
        m = fmaf(__builtin_bit_cast(float, (unsigned)(wrd) & 0xffff0000u), av[h + 1], m);
#pragma unroll
        for (int hh = 0; hh < 8; hh++) {
            unsigned uw = up[hh * 64];                    // conflict-free ds_read
            ACC2(uw, 2 * hh)
        }
#undef ACC2
        MSGout[(size_t)e * EMB + o] = m;                  // coalesced 256B store
    }
}

// ---------------------------------------------------------------------------
// conv2 node update: gather MSGa via dst-list (LDS ds_add), + X1@root2+bias2,
// relu, atomicMax into POOL. 625 blocks x 512 (same row ownership as f).
// ---------------------------------------------------------------------------
__global__ void __launch_bounds__(512) k_upd2(P p) {
    __shared__ float Xt[16][65];
    const int b = blockIdx.x, t = threadIdx.x;
    const int n0 = b * 16;
    const int w = t >> 6, l = t & 63;
    int dcv = p.dcnt[b];
    for (int idx = t; idx < 16 * 64; idx += 512) Xt[idx >> 6][idx & 63] = 0.f;
    __syncthreads();
    for (int jj = w; jj < dcv; jj += 8) {
        int q = __builtin_amdgcn_readfirstlane(jj);
        int mt = p.dstm[(size_t)b * CAP + q];
        int e = mt >> 4, dloc = mt & 15;
        atomicAdd(&Xt[dloc][l], p.MSGa[(size_t)e * EMB + l]);
    }
    __syncthreads();
    for (int idx = t; idx < 16 * 64; idx += 512) {
        int j = idx >> 6, o = idx & 63;
        int n = n0 + j;
        float s = Xt[j][o] + p.bias2[o];
        const float* xr = p.X1 + (size_t)n * EMB;     // wave-uniform -> s_loads
#pragma unroll
        for (int i = 0; i < EMB; i++) s += xr[i] * p.root2[i * EMB + o];
        s = fmaxf(s, 0.f);
        atomicMax((unsigned*)&p.POOL[p.batch[n] * EMB + o], __float_as_uint(s));
    }
}

// --- head: block g, lane o2 computes h[g,o2]; shuffle-reduce h·lin1_w
__global__ void k_head(P p) {
    int g = blockIdx.x, o2 = threadIdx.x;             // 64 blocks x 64 threads
    float h = p.lin0_b[o2];
    const float* Pg = p.POOL + g * EMB;
    for (int o = 0; o < EMB; o++) h += Pg[o] * p.lin0_w[o * EMB + o2];
    float v = h * p.lin1_w[o2];
#pragma unroll
    for (int off = 32; off; off >>= 1) v += __shfl_down(v, off, 64);
    if (o2 == 0) p.out[g] = v + p.lin1_b[0];
}

extern "C" void kernel_launch(void* const* d_in, const int* in_sizes, int n_in,
                              void* d_out, int out_size, void* d_ws, size_t ws_size,
                              hipStream_t stream) {
    P p;
    p.x_p    = (const float*)d_in[0];
    p.ea     = (const float*)d_in[2];
    const int* eidx = (const int*)d_in[4];
    p.src    = eidx;                   // edge_index_p[0]
    p.dst    = eidx + N_EDGES;         // edge_index_p[1]
    p.batch  = (const int*)d_in[5];
    p.nn0_w1 = (const float*)d_in[6];  p.nn0_b1 = (const float*)d_in[7];
    p.nn0_w2 = (const float*)d_in[8];  p.nn0_b2 = (const float*)d_in[9];
    p.nn1_w1 = (const float*)d_in[10]; p.nn1_b1 = (const float*)d_in[11];
    p.nn1_w2 = (const float*)d_in[12]; p.nn1_b2 = (const float*)d_in[13];
    p.root0  = (const float*)d_in[14]; p.bias0  = (const float*)d_in[15];
    p.root1  = (const float*)d_in[16]; p.bias1  = (const float*)d_in[17];
    p.root2  = (const float*)d_in[18]; p.bias2  = (const float*)d_in[19];
    p.lin0_w = (const float*)d_in[20]; p.lin0_b = (const float*)d_in[21];
    p.lin1_w = (const float*)d_in[22]; p.lin1_b = (const float*)d_in[23];
    p.out    = (float*)d_out;

    // workspace (~26 MB); no memsets, no prep — all init inside f0
    char* ws = (char*)d_ws;
    p.cnt   = (int*)ws;            ws += 2560;       // 625 ints, padded
    p.dcnt  = (int*)ws;            ws += 2560;
    p.metap = (int*)ws;            ws += (size_t)NBUCK * CAP * 4;
    p.dstm  = (int*)ws;            ws += (size_t)NBUCK * CAP * 4;
    p.A1p   = (float*)ws;          ws += (size_t)NBUCK * CAP * HID * 4;
    p.MSGa  = (float*)ws;          ws += (size_t)N_EDGES * EMB * 4;
    p.MSGb  = (float*)ws;          ws += (size_t)N_EDGES * EMB * 4;
    p.X0    = (float*)ws;          ws += (size_t)N_NODES * EMB * 4;
    p.X1    = (float*)ws;          ws += (size_t)N_NODES * EMB * 4;
    p.POOL  = (float*)ws;          ws += (size_t)NGRAPH * EMB * 4;

    k_fused<0><<<NBUCK, 512, 0, stream>>>(p);
    k_fused<1><<<NBUCK, 512, 0, stream>>>(p);
    k_fused<2><<<NBUCK, 512, 0, stream>>>(p);
    k_upd2<<<NBUCK, 512, 0, stream>>>(p);
    k_head<<<NGRAPH, 64, 0, stream>>>(p);
}

// Round 12
// 214.669 us; speedup vs baseline: 1.1269x; 1.1269x over previous
//
#include <hip/hip_runtime.h>
#include <hip/hip_bf16.h>

#define N_NODES 10000
#define N_EDGES 30000
#define F_NODE  32
#define F_EDGE  8
#define EMB     64
#define HID     16
#define NGRAPH  64
#define NBUCK   625              // 10000/16 exact
#define CAP     128              // slots per src-bucket (mean 48; held r6-r11)
#define NCOL    1088             // 1024 U cols + 64 XB cols
#define ROWW    514              // U_lds row stride in words (514%32=2 -> bank spread; r7-verified)

typedef __attribute__((ext_vector_type(8))) short short8;   // 8 bf16 (MFMA A/B frag)
typedef __attribute__((ext_vector_type(4))) float f32x4;    // MFMA C/D frag

__device__ __forceinline__ unsigned short f2b(float f) {
    __hip_bfloat16 h = __float2bfloat16(f);
    return __builtin_bit_cast(unsigned short, h);
}

struct P {
    const float *x_p, *ea;
    const int *src, *dst, *batch;
    const float *nn0_w1, *nn0_b1, *nn0_w2, *nn0_b2;
    const float *nn1_w1, *nn1_b1, *nn1_w2, *nn1_b2;
    const float *root0, *bias0, *root1, *bias1, *root2, *bias2;
    const float *lin0_w, *lin0_b, *lin1_w, *lin1_b;
    float *out;
    int *cnt, *metap;
    float *A1p;
    unsigned short *W2p0, *W2p1;
    float *AGGa, *AGGb, *X0, *X1;
};

// ---------------------------------------------------------------------------
// prep (r10-proven): W2p permutes + AGGa zero.
//   [0,136)    W2p0 (K=32), transposed tile order (r7 conflict fix):
//              tile T<64 holds {o=(T>>4)*16+lr, h=T&15}; T>=64 are b2 cols.
//   [136,408)  W2p1 (K=64), same order.
//   [408,568)  zero AGGa (float4).
// ---------------------------------------------------------------------------
__global__ void __launch_bounds__(256) k_prep(P p) {
    int b = blockIdx.x, t = threadIdx.x;
    if (b < 136) {                              // W2p0 (K=32): 34816 elems
        int i = b * 256 + t;
        if (i >= NCOL * F_NODE) return;
        int rt = i >> 5, k = i & 31;
        float v;
        if (rt < 1024) {
            int T = rt >> 4, lr = rt & 15;
            int o = ((T >> 4) << 4) + lr, h = T & 15;
            v = p.nn0_w2[h * (F_NODE * EMB) + k * EMB + o];
        } else {
            v = p.nn0_b2[k * EMB + (rt - 1024)];
        }
        p.W2p0[i] = f2b(v);
    } else if (b < 408) {                       // W2p1 (K=64): 69632 elems
        int i = (b - 136) * 256 + t;
        if (i >= NCOL * EMB) return;
        int rt = i >> 6, k = i & 63;
        float v;
        if (rt < 1024) {
            int T = rt >> 4, lr = rt & 15;
            int o = ((T >> 4) << 4) + lr, h = T & 15;
            v = p.nn1_w2[h * (EMB * EMB) + k * EMB + o];
        } else {
            v = p.nn1_b2[k * EMB + (rt - 1024)];
        }
        p.W2p1[i] = f2b(v);
    } else {                                    // zero AGGa
        int idx = (b - 408) * 256 + t;
        float4* Z = (float4*)p.AGGa;
        const float4 z4 = {0.f, 0.f, 0.f, 0.f};
        for (int i = idx; i < (N_NODES * EMB) / 4; i += 160 * 256) Z[i] = z4;
    }
}

// ---------------------------------------------------------------------------
// Fused conv kernel (r10-proven structure), 512 threads, block b owns nodes
// [16b,16b+16):
//   CONV==0: zero own AGGb rows; scan src (int4) -> LDS bucket; edge-MLP for
//     own edges (a0 -> LDS, a1+meta+cnt -> block-owned global).
//   CONV>0 prologue: X_{c-1} = relu(AGG+x@root+bias); conv1 re-zeros AGGa.
//   MFMA: U tile -> LDS; word = row*514+(h>>1)*64+o; conflict-free (r7).
//   Edge loop: msg = XB + sum_h A*U (2 independent fma chains) ->
//     atomicAdd AGG_out[dst].
// AGG ping-pong: conv0->AGGa, conv1->AGGb (zeroes AGGa), conv2->AGGa.
// ---------------------------------------------------------------------------
template <int CONV>
__global__ void __launch_bounds__(512) k_fused(P p) {
    constexpr int K = (CONV == 0) ? F_NODE : EMB;
    __shared__ unsigned short U2[16 * 2 * ROWW];   // 32.9 KB
    __shared__ float XB_l[16][65];
    __shared__ float Xt[16][65];
    __shared__ float A0l[CAP][HID];                // f0 only (DCE'd in f1/f2)
    __shared__ int lds_e[CAP];
    __shared__ int meta_l[CAP];
    __shared__ int lcnt;
    const int b = blockIdx.x, t = threadIdx.x;
    const int n0 = b * 16;
    const int w = t >> 6, l = t & 63;
    const int lrow = l & 15, lk4 = l >> 4;
    int cnt = 0;

    if (CONV == 0) {
        float4* Zb = (float4*)(p.AGGb + (size_t)n0 * EMB);
        const float4 z4 = {0.f, 0.f, 0.f, 0.f};
        for (int idx = t; idx < 16 * EMB / 4; idx += 512) Zb[idx] = z4;
        if (t == 0) lcnt = 0;
        __syncthreads();
        const int4* s4 = (const int4*)p.src;
        for (int i = t; i < N_EDGES / 4; i += 512) {
            int4 v = s4[i];
            int e0 = i * 4;
            if ((v.x >> 4) == b) { int sl = atomicAdd(&lcnt, 1); if (sl < CAP) lds_e[sl] = ((e0    ) << 4) | (v.x & 15); }
            if ((v.y >> 4) == b) { int sl = atomicAdd(&lcnt, 1); if (sl < CAP) lds_e[sl] = ((e0 + 1) << 4) | (v.y & 15); }
            if ((v.z >> 4) == b) { int sl = atomicAdd(&lcnt, 1); if (sl < CAP) lds_e[sl] = ((e0 + 2) << 4) | (v.z & 15); }
            if ((v.w >> 4) == b) { int sl = atomicAdd(&lcnt, 1); if (sl < CAP) lds_e[sl] = ((e0 + 3) << 4) | (v.w & 15); }
        }
        __syncthreads();
        cnt = lcnt; if (cnt > CAP) cnt = CAP;
        if (t == 0) p.cnt[b] = cnt;
        if (t < cnt) {
            int pk = lds_e[t];
            int e = pk >> 4, sloc = pk & 15;
            int mt = p.dst[e] * 16 + sloc;
            meta_l[t] = mt;
            p.metap[(size_t)b * CAP + t] = mt;
            const float4* ea4 = (const float4*)(p.ea + (size_t)e * F_EDGE);
            float4 ef0 = ea4[0], ef1 = ea4[1];
            float fv[F_EDGE] = {ef0.x, ef0.y, ef0.z, ef0.w, ef1.x, ef1.y, ef1.z, ef1.w};
            float a1v[HID];
#pragma unroll
            for (int h = 0; h < HID; h++) {
                float s0 = p.nn0_b1[h], s1 = p.nn1_b1[h];
#pragma unroll
                for (int i = 0; i < F_EDGE; i++) {
                    s0 += fv[i] * p.nn0_w1[i * HID + h];
                    s1 += fv[i] * p.nn1_w1[i * HID + h];
                }
                A0l[t][h] = fmaxf(s0, 0.f);
                a1v[h] = fmaxf(s1, 0.f);
            }
            float4* A1g = (float4*)(p.A1p + ((size_t)b * CAP + t) * HID);
#pragma unroll
            for (int j = 0; j < 4; j++)
                A1g[j] = float4{a1v[4 * j], a1v[4 * j + 1], a1v[4 * j + 2], a1v[4 * j + 3]};
        }
        // A0l/meta_l visibility covered by the post-MFMA __syncthreads
    }

    if (CONV > 0) {      // prologue: previous conv's node update for own rows
        const float* aggIn = (CONV == 1) ? p.AGGa : p.AGGb;
        const float* rt = (CONV == 1) ? p.root0 : p.root1;
        const float* bs = (CONV == 1) ? p.bias0 : p.bias1;
        constexpr int IN = (CONV == 1) ? F_NODE : EMB;
        for (int idx = t; idx < 16 * 64; idx += 512) {
            int j = idx >> 6, o = idx & 63;
            int n = n0 + j;
            float s = aggIn[n * EMB + o] + bs[o];
            const float* xr = (CONV == 1) ? (p.x_p + (size_t)n * IN)
                                          : (p.X0 + (size_t)n * IN);
#pragma unroll
            for (int i = 0; i < IN; i++) s += xr[i] * rt[i * EMB + o];
            float sv = fmaxf(s, 0.f);
            Xt[j][o] = sv;
            if (CONV == 1) { p.X0[n * EMB + o] = sv; p.AGGa[n * EMB + o] = 0.f; }
            else           { p.X1[n * EMB + o] = sv; }
        }
        __syncthreads();
        cnt = p.cnt[b];
    }

    // ---- MFMA: C[16 x 1088] = X_tile @ W2p^T  (tiles T = w + 8i)
    short8 afr[K / 32];
    if (CONV == 0) {
        const float* xp = p.x_p + (size_t)(n0 + lrow) * F_NODE + lk4 * 8;
#pragma unroll
        for (int q = 0; q < 8; q++) afr[0][q] = (short)f2b(xp[q]);
    } else {
#pragma unroll
        for (int kk = 0; kk < K / 32; kk++)
#pragma unroll
            for (int q = 0; q < 8; q++)
                afr[kk][q] = (short)f2b(Xt[lrow][kk * 32 + lk4 * 8 + q]);
    }
    const unsigned short* W2p = (CONV == 0) ? p.W2p0 : p.W2p1;
    for (int i = 0; i <= 8; i++) {
        int T = w + 8 * i;
        if (T >= 68) break;
        short8 bfr[K / 32];
#pragma unroll
        for (int kk = 0; kk < K / 32; kk++)
            bfr[kk] = *reinterpret_cast<const short8*>(
                W2p + (size_t)(T * 16 + lrow) * K + kk * 32 + lk4 * 8);
        f32x4 acc = {0.f, 0.f, 0.f, 0.f};
#pragma unroll
        for (int kk = 0; kk < K / 32; kk++)
            acc = __builtin_amdgcn_mfma_f32_16x16x32_bf16(afr[kk], bfr[kk], acc, 0, 0, 0);
        if (T < 64) {
            int h = T & 15, hw = h >> 1, hb = h & 1;
            int ob = ((T >> 4) << 4) + lrow;          // this lane's o
#pragma unroll
            for (int r = 0; r < 4; r++)
                U2[(lk4 * 4 + r) * (2 * ROWW) + hw * 128 + ob * 2 + hb] = f2b(acc[r]);
        } else {
            int col = (T - 64) * 16 + lrow;
#pragma unroll
            for (int r = 0; r < 4; r++)
                XB_l[lk4 * 4 + r][col] = acc[r];
        }
    }
    __syncthreads();

    // ---- edge loop (8 waves interleave); 2 independent fma chains per edge
    float* aggOut = (CONV == 1) ? p.AGGb : p.AGGa;
    const size_t base = (size_t)b * CAP;
    const int o = l;
#pragma unroll 2
    for (int qi = w; qi < cnt; qi += 8) {
        int q = __builtin_amdgcn_readfirstlane(qi);
        int mt;
        float av[HID];
        if (CONV == 0) {
            mt = meta_l[q];
            const float4* a4 = (const float4*)A0l[q];     // LDS broadcast b128
            float4 u0 = a4[0], u1 = a4[1], u2 = a4[2], u3 = a4[3];
            av[0]=u0.x; av[1]=u0.y; av[2]=u0.z; av[3]=u0.w;
            av[4]=u1.x; av[5]=u1.y; av[6]=u1.z; av[7]=u1.w;
            av[8]=u2.x; av[9]=u2.y; av[10]=u2.z; av[11]=u2.w;
            av[12]=u3.x; av[13]=u3.y; av[14]=u3.z; av[15]=u3.w;
        } else {
            mt = p.metap[base + q];                       // s_load (q uniform)
            const float* Ae = p.A1p + (base + q) * HID;   // contiguous s_loads
#pragma unroll
            for (int h = 0; h < HID; h++) av[h] = Ae[h];
        }
        int sloc = mt & 15, dd = mt >> 4;
        const unsigned* up = reinterpret_cast<const unsigned*>(U2) + sloc * ROWW + o;
        float m0 = XB_l[sloc][o], m1 = 0.f;
#define ACC2(dst_, wrd, h)                                                            \
        dst_ = fmaf(__builtin_bit_cast(float, (unsigned)(wrd) << 16), av[h], dst_);   \
        dst_ = fmaf(__builtin_bit_cast(float, (unsigned)(wrd) & 0xffff0000u), av[h + 1], dst_);
#pragma unroll
        for (int hh = 0; hh < 4; hh++) {
            unsigned ua = up[hh * 64];                    // conflict-free ds_read
            unsigned ub = up[(hh + 4) * 64];
            ACC2(m0, ua, 2 * hh)
            ACC2(m1, ub, 2 * (hh + 4))
        }
#undef ACC2
        atomicAdd(&aggOut[(size_t)dd * EMB + o], m0 + m1);
    }
}

// ---------------------------------------------------------------------------
// Tail: conv2 node update + per-graph max pool + head, fused WITHOUT any
// cross-block sync: batch is SORTED, so block g owns exactly the node range
// [lo,hi) of graph g (binary search). Pool lives in block LDS.
// ---------------------------------------------------------------------------
__global__ void __launch_bounds__(256) k_tail(P p) {
    __shared__ unsigned pool[EMB];
    const int g = blockIdx.x, t = threadIdx.x;
    const int w = t >> 6, o = t & 63;
    if (t < EMB) pool[t] = 0u;                    // relu outputs >= 0
    __syncthreads();
    // binary search node range of graph g (uniform -> scalar loads)
    int lo = 0, hi = N_NODES;
    while (lo < hi) { int mid = (lo + hi) >> 1; if (p.batch[mid] < g) lo = mid + 1; else hi = mid; }
    int lo2 = lo, hi2 = N_NODES;
    while (lo2 < hi2) { int mid = (lo2 + hi2) >> 1; if (p.batch[mid] < g + 1) lo2 = mid + 1; else hi2 = mid; }
    const float b2 = p.bias2[o];
    for (int n0 = lo + w; n0 < lo2; n0 += 4) {    // wave per node
        int n = __builtin_amdgcn_readfirstlane(n0);
        float s = p.AGGa[(size_t)n * EMB + o] + b2;
        const float* xr = p.X1 + (size_t)n * EMB; // wave-uniform -> s_loads
#pragma unroll
        for (int i = 0; i < EMB; i++) s += xr[i] * p.root2[i * EMB + o];
        s = fmaxf(s, 0.f);
        atomicMax(&pool[o], __float_as_uint(s));  // LDS atomic
    }
    __syncthreads();
    if (t < EMB) {                                // wave 0: head
        int o2 = t;
        float h = p.lin0_b[o2];
#pragma unroll 8
        for (int oo = 0; oo < EMB; oo++)
            h += __uint_as_float(pool[oo]) * p.lin0_w[oo * EMB + o2];
        float v = h * p.lin1_w[o2];
#pragma unroll
        for (int off = 32; off; off >>= 1) v += __shfl_down(v, off, 64);
        if (o2 == 0) p.out[g] = v + p.lin1_b[0];
    }
}

extern "C" void kernel_launch(void* const* d_in, const int* in_sizes, int n_in,
                              void* d_out, int out_size, void* d_ws, size_t ws_size,
                              hipStream_t stream) {
    P p;
    p.x_p    = (const float*)d_in[0];
    p.ea     = (const float*)d_in[2];
    const int* eidx = (const int*)d_in[4];
    p.src    = eidx;                   // edge_index_p[0]
    p.dst    = eidx + N_EDGES;         // edge_index_p[1]
    p.batch  = (const int*)d_in[5];
    p.nn0_w1 = (const float*)d_in[6];  p.nn0_b1 = (const float*)d_in[7];
    p.nn0_w2 = (const float*)d_in[8];  p.nn0_b2 = (const float*)d_in[9];
    p.nn1_w1 = (const float*)d_in[10]; p.nn1_b1 = (const float*)d_in[11];
    p.nn1_w2 = (const float*)d_in[12]; p.nn1_b2 = (const float*)d_in[13];
    p.root0  = (const float*)d_in[14]; p.bias0  = (const float*)d_in[15];
    p.root1  = (const float*)d_in[16]; p.bias1  = (const float*)d_in[17];
    p.root2  = (const float*)d_in[18]; p.bias2  = (const float*)d_in[19];
    p.lin0_w = (const float*)d_in[20]; p.lin0_b = (const float*)d_in[21];
    p.lin1_w = (const float*)d_in[22]; p.lin1_b = (const float*)d_in[23];
    p.out    = (float*)d_out;

    // workspace (~16 MB). AGGa zeroed by prep; AGGb by f0; no POOL buffer.
    char* ws = (char*)d_ws;
    p.AGGa   = (float*)ws;          ws += (size_t)N_NODES * EMB * 4;
    p.AGGb   = (float*)ws;          ws += (size_t)N_NODES * EMB * 4;
    p.cnt    = (int*)ws;            ws += 2560;      // 625 ints, padded
    p.metap  = (int*)ws;            ws += (size_t)NBUCK * CAP * 4;
    p.A1p    = (float*)ws;          ws += (size_t)NBUCK * CAP * HID * 4;
    p.W2p0   = (unsigned short*)ws; ws += (size_t)NCOL * F_NODE * 2;
    p.W2p1   = (unsigned short*)ws; ws += (size_t)NCOL * EMB * 2;
    p.X0     = (float*)ws;          ws += (size_t)N_NODES * EMB * 4;
    p.X1     = (float*)ws;          ws += (size_t)N_NODES * EMB * 4;

    k_prep<<<568, 256, 0, stream>>>(p);
    k_fused<0><<<NBUCK, 512, 0, stream>>>(p);
    k_fused<1><<<NBUCK, 512, 0, stream>>>(p);
    k_fused<2><<<NBUCK, 512, 0, stream>>>(p);
    k_tail<<<NGRAPH, 256, 0, stream>>>(p);
}

// Round 13
// 206.732 us; speedup vs baseline: 1.1701x; 1.0384x over previous
//
#include <hip/hip_runtime.h>
#include <hip/hip_bf16.h>

#define N_NODES 10000
#define N_EDGES 30000
#define F_NODE  32
#define F_EDGE  8
#define EMB     64
#define HID     16
#define NGRAPH  64
#define NBUCK   625              // 10000/16 exact
#define CAP     128              // slots per src-bucket (mean 48; held r6-r12)
#define NCOL    1088             // 1024 U cols + 64 XB cols
#define ROWW    514              // U_lds row stride in words (514%32=2 -> bank spread; r7-verified)

typedef __attribute__((ext_vector_type(8))) short short8;   // 8 bf16 (MFMA A/B frag)
typedef __attribute__((ext_vector_type(4))) float f32x4;    // MFMA C/D frag

__device__ __forceinline__ unsigned short f2b(float f) {
    __hip_bfloat16 h = __float2bfloat16(f);
    return __builtin_bit_cast(unsigned short, h);
}

struct P {
    const float *x_p, *ea;
    const int *src, *dst, *batch;
    const float *nn0_w1, *nn0_b1, *nn0_w2, *nn0_b2;
    const float *nn1_w1, *nn1_b1, *nn1_w2, *nn1_b2;
    const float *root0, *bias0, *root1, *bias1, *root2, *bias2;
    const float *lin0_w, *lin0_b, *lin1_w, *lin1_b;
    float *out;
    int *cnt, *metap;
    float *A1p;
    unsigned short *W2p0, *W2p1;
    float *AGGa, *AGGb, *X0, *X1;
};

// ---------------------------------------------------------------------------
// prep (r10-proven): W2p permutes + AGGa zero.
// ---------------------------------------------------------------------------
__global__ void __launch_bounds__(256) k_prep(P p) {
    int b = blockIdx.x, t = threadIdx.x;
    if (b < 136) {                              // W2p0 (K=32): 34816 elems
        int i = b * 256 + t;
        if (i >= NCOL * F_NODE) return;
        int rt = i >> 5, k = i & 31;
        float v;
        if (rt < 1024) {
            int T = rt >> 4, lr = rt & 15;
            int o = ((T >> 4) << 4) + lr, h = T & 15;
            v = p.nn0_w2[h * (F_NODE * EMB) + k * EMB + o];
        } else {
            v = p.nn0_b2[k * EMB + (rt - 1024)];
        }
        p.W2p0[i] = f2b(v);
    } else if (b < 408) {                       // W2p1 (K=64): 69632 elems
        int i = (b - 136) * 256 + t;
        if (i >= NCOL * EMB) return;
        int rt = i >> 6, k = i & 63;
        float v;
        if (rt < 1024) {
            int T = rt >> 4, lr = rt & 15;
            int o = ((T >> 4) << 4) + lr, h = T & 15;
            v = p.nn1_w2[h * (EMB * EMB) + k * EMB + o];
        } else {
            v = p.nn1_b2[k * EMB + (rt - 1024)];
        }
        p.W2p1[i] = f2b(v);
    } else {                                    // zero AGGa
        int idx = (b - 408) * 256 + t;
        float4* Z = (float4*)p.AGGa;
        const float4 z4 = {0.f, 0.f, 0.f, 0.f};
        for (int i = idx; i < (N_NODES * EMB) / 4; i += 160 * 256) Z[i] = z4;
    }
}

// ---------------------------------------------------------------------------
// Fused conv kernel (r10-proven structure), 512 threads, block b owns nodes
// [16b,16b+16). See r12 comments; unchanged.
// ---------------------------------------------------------------------------
template <int CONV>
__global__ void __launch_bounds__(512) k_fused(P p) {
    constexpr int K = (CONV == 0) ? F_NODE : EMB;
    __shared__ unsigned short U2[16 * 2 * ROWW];   // 32.9 KB
    __shared__ float XB_l[16][65];
    __shared__ float Xt[16][65];
    __shared__ float A0l[CAP][HID];                // f0 only (DCE'd in f1/f2)
    __shared__ int lds_e[CAP];
    __shared__ int meta_l[CAP];
    __shared__ int lcnt;
    const int b = blockIdx.x, t = threadIdx.x;
    const int n0 = b * 16;
    const int w = t >> 6, l = t & 63;
    const int lrow = l & 15, lk4 = l >> 4;
    int cnt = 0;

    if (CONV == 0) {
        float4* Zb = (float4*)(p.AGGb + (size_t)n0 * EMB);
        const float4 z4 = {0.f, 0.f, 0.f, 0.f};
        for (int idx = t; idx < 16 * EMB / 4; idx += 512) Zb[idx] = z4;
        if (t == 0) lcnt = 0;
        __syncthreads();
        const int4* s4 = (const int4*)p.src;
        for (int i = t; i < N_EDGES / 4; i += 512) {
            int4 v = s4[i];
            int e0 = i * 4;
            if ((v.x >> 4) == b) { int sl = atomicAdd(&lcnt, 1); if (sl < CAP) lds_e[sl] = ((e0    ) << 4) | (v.x & 15); }
            if ((v.y >> 4) == b) { int sl = atomicAdd(&lcnt, 1); if (sl < CAP) lds_e[sl] = ((e0 + 1) << 4) | (v.y & 15); }
            if ((v.z >> 4) == b) { int sl = atomicAdd(&lcnt, 1); if (sl < CAP) lds_e[sl] = ((e0 + 2) << 4) | (v.z & 15); }
            if ((v.w >> 4) == b) { int sl = atomicAdd(&lcnt, 1); if (sl < CAP) lds_e[sl] = ((e0 + 3) << 4) | (v.w & 15); }
        }
        __syncthreads();
        cnt = lcnt; if (cnt > CAP) cnt = CAP;
        if (t == 0) p.cnt[b] = cnt;
        if (t < cnt) {
            int pk = lds_e[t];
            int e = pk >> 4, sloc = pk & 15;
            int mt = p.dst[e] * 16 + sloc;
            meta_l[t] = mt;
            p.metap[(size_t)b * CAP + t] = mt;
            const float4* ea4 = (const float4*)(p.ea + (size_t)e * F_EDGE);
            float4 ef0 = ea4[0], ef1 = ea4[1];
            float fv[F_EDGE] = {ef0.x, ef0.y, ef0.z, ef0.w, ef1.x, ef1.y, ef1.z, ef1.w};
            float a1v[HID];
#pragma unroll
            for (int h = 0; h < HID; h++) {
                float s0 = p.nn0_b1[h], s1 = p.nn1_b1[h];
#pragma unroll
                for (int i = 0; i < F_EDGE; i++) {
                    s0 += fv[i] * p.nn0_w1[i * HID + h];
                    s1 += fv[i] * p.nn1_w1[i * HID + h];
                }
                A0l[t][h] = fmaxf(s0, 0.f);
                a1v[h] = fmaxf(s1, 0.f);
            }
            float4* A1g = (float4*)(p.A1p + ((size_t)b * CAP + t) * HID);
#pragma unroll
            for (int j = 0; j < 4; j++)
                A1g[j] = float4{a1v[4 * j], a1v[4 * j + 1], a1v[4 * j + 2], a1v[4 * j + 3]};
        }
    }

    if (CONV > 0) {      // prologue: previous conv's node update for own rows
        const float* aggIn = (CONV == 1) ? p.AGGa : p.AGGb;
        const float* rt = (CONV == 1) ? p.root0 : p.root1;
        const float* bs = (CONV == 1) ? p.bias0 : p.bias1;
        constexpr int IN = (CONV == 1) ? F_NODE : EMB;
        for (int idx = t; idx < 16 * 64; idx += 512) {
            int j = idx >> 6, o = idx & 63;
            int n = n0 + j;
            float s = aggIn[n * EMB + o] + bs[o];
            const float* xr = (CONV == 1) ? (p.x_p + (size_t)n * IN)
                                          : (p.X0 + (size_t)n * IN);
#pragma unroll
            for (int i = 0; i < IN; i++) s += xr[i] * rt[i * EMB + o];
            float sv = fmaxf(s, 0.f);
            Xt[j][o] = sv;
            if (CONV == 1) { p.X0[n * EMB + o] = sv; p.AGGa[n * EMB + o] = 0.f; }
            else           { p.X1[n * EMB + o] = sv; }
        }
        __syncthreads();
        cnt = p.cnt[b];
    }

    // ---- MFMA: C[16 x 1088] = X_tile @ W2p^T  (tiles T = w + 8i)
    short8 afr[K / 32];
    if (CONV == 0) {
        const float* xp = p.x_p + (size_t)(n0 + lrow) * F_NODE + lk4 * 8;
#pragma unroll
        for (int q = 0; q < 8; q++) afr[0][q] = (short)f2b(xp[q]);
    } else {
#pragma unroll
        for (int kk = 0; kk < K / 32; kk++)
#pragma unroll
            for (int q = 0; q < 8; q++)
                afr[kk][q] = (short)f2b(Xt[lrow][kk * 32 + lk4 * 8 + q]);
    }
    const unsigned short* W2p = (CONV == 0) ? p.W2p0 : p.W2p1;
    for (int i = 0; i <= 8; i++) {
        int T = w + 8 * i;
        if (T >= 68) break;
        short8 bfr[K / 32];
#pragma unroll
        for (int kk = 0; kk < K / 32; kk++)
            bfr[kk] = *reinterpret_cast<const short8*>(
                W2p + (size_t)(T * 16 + lrow) * K + kk * 32 + lk4 * 8);
        f32x4 acc = {0.f, 0.f, 0.f, 0.f};
#pragma unroll
        for (int kk = 0; kk < K / 32; kk++)
            acc = __builtin_amdgcn_mfma_f32_16x16x32_bf16(afr[kk], bfr[kk], acc, 0, 0, 0);
        if (T < 64) {
            int h = T & 15, hw = h >> 1, hb = h & 1;
            int ob = ((T >> 4) << 4) + lrow;          // this lane's o
#pragma unroll
            for (int r = 0; r < 4; r++)
                U2[(lk4 * 4 + r) * (2 * ROWW) + hw * 128 + ob * 2 + hb] = f2b(acc[r]);
        } else {
            int col = (T - 64) * 16 + lrow;
#pragma unroll
            for (int r = 0; r < 4; r++)
                XB_l[lk4 * 4 + r][col] = acc[r];
        }
    }
    __syncthreads();

    // ---- edge loop (8 waves interleave); 2 independent fma chains per edge
    float* aggOut = (CONV == 1) ? p.AGGb : p.AGGa;
    const size_t base = (size_t)b * CAP;
    const int o = l;
#pragma unroll 2
    for (int qi = w; qi < cnt; qi += 8) {
        int q = __builtin_amdgcn_readfirstlane(qi);
        int mt;
        float av[HID];
        if (CONV == 0) {
            mt = meta_l[q];
            const float4* a4 = (const float4*)A0l[q];     // LDS broadcast b128
            float4 u0 = a4[0], u1 = a4[1], u2 = a4[2], u3 = a4[3];
            av[0]=u0.x; av[1]=u0.y; av[2]=u0.z; av[3]=u0.w;
            av[4]=u1.x; av[5]=u1.y; av[6]=u1.z; av[7]=u1.w;
            av[8]=u2.x; av[9]=u2.y; av[10]=u2.z; av[11]=u2.w;
            av[12]=u3.x; av[13]=u3.y; av[14]=u3.z; av[15]=u3.w;
        } else {
            mt = p.metap[base + q];                       // s_load (q uniform)
            const float* Ae = p.A1p + (base + q) * HID;   // contiguous s_loads
#pragma unroll
            for (int h = 0; h < HID; h++) av[h] = Ae[h];
        }
        int sloc = mt & 15, dd = mt >> 4;
        const unsigned* up = reinterpret_cast<const unsigned*>(U2) + sloc * ROWW + o;
        float m0 = XB_l[sloc][o], m1 = 0.f;
#define ACC2(dst_, wrd, h)                                                            \
        dst_ = fmaf(__builtin_bit_cast(float, (unsigned)(wrd) << 16), av[h], dst_);   \
        dst_ = fmaf(__builtin_bit_cast(float, (unsigned)(wrd) & 0xffff0000u), av[h + 1], dst_);
#pragma unroll
        for (int hh = 0; hh < 4; hh++) {
            unsigned ua = up[hh * 64];                    // conflict-free ds_read
            unsigned ub = up[(hh + 4) * 64];
            ACC2(m0, ua, 2 * hh)
            ACC2(m1, ub, 2 * (hh + 4))
        }
#undef ACC2
        atomicAdd(&aggOut[(size_t)dd * EMB + o], m0 + m1);
    }
}

// ---------------------------------------------------------------------------
// Tail v2 (r12 fix): conv2 update + per-graph max pool + head. 64 blocks x
// 512 threads; wave w takes every 8th node; root2 column in registers;
// 4 independent fma accumulators (chain 64 -> 16).
// ---------------------------------------------------------------------------
__global__ void __launch_bounds__(512) k_tail(P p) {
    __shared__ unsigned pool[EMB];
    const int g = blockIdx.x, t = threadIdx.x;
    const int w = t >> 6, o = t & 63;
    if (t < EMB) pool[t] = 0u;                    // relu outputs >= 0
    __syncthreads();
    int lo = 0, hi = N_NODES;
    while (lo < hi) { int mid = (lo + hi) >> 1; if (p.batch[mid] < g) lo = mid + 1; else hi = mid; }
    int lo2 = lo, hi2 = N_NODES;
    while (lo2 < hi2) { int mid = (lo2 + hi2) >> 1; if (p.batch[mid] < g + 1) lo2 = mid + 1; else hi2 = mid; }
    const float b2 = p.bias2[o];
    float rcol[EMB];                              // root2 column o in registers
#pragma unroll
    for (int i = 0; i < EMB; i++) rcol[i] = p.root2[i * EMB + o];
    float mx = 0.f;
    for (int nn = lo + w; nn < lo2; nn += 8) {    // wave w: every 8th node
        int n = __builtin_amdgcn_readfirstlane(nn);
        const float* xr = p.X1 + (size_t)n * EMB; // wave-uniform -> s_loads
        float s0 = p.AGGa[(size_t)n * EMB + o] + b2;
        float s1 = 0.f, s2 = 0.f, s3 = 0.f;
#pragma unroll
        for (int i = 0; i < EMB; i += 4) {        // 4 independent chains
            s0 = fmaf(xr[i + 0], rcol[i + 0], s0);
            s1 = fmaf(xr[i + 1], rcol[i + 1], s1);
            s2 = fmaf(xr[i + 2], rcol[i + 2], s2);
            s3 = fmaf(xr[i + 3], rcol[i + 3], s3);
        }
        mx = fmaxf(mx, fmaxf((s0 + s1) + (s2 + s3), 0.f));
    }
    atomicMax(&pool[o], __float_as_uint(mx));     // LDS atomic, 8 per column
    __syncthreads();
    if (t < EMB) {                                // wave 0: head
        int o2 = t;
        float h = p.lin0_b[o2];
#pragma unroll 8
        for (int oo = 0; oo < EMB; oo++)
            h += __uint_as_float(pool[oo]) * p.lin0_w[oo * EMB + o2];
        float v = h * p.lin1_w[o2];
#pragma unroll
        for (int off = 32; off; off >>= 1) v += __shfl_down(v, off, 64);
        if (o2 == 0) p.out[g] = v + p.lin1_b[0];
    }
}

extern "C" void kernel_launch(void* const* d_in, const int* in_sizes, int n_in,
                              void* d_out, int out_size, void* d_ws, size_t ws_size,
                              hipStream_t stream) {
    P p;
    p.x_p    = (const float*)d_in[0];
    p.ea     = (const float*)d_in[2];
    const int* eidx = (const int*)d_in[4];
    p.src    = eidx;                   // edge_index_p[0]
    p.dst    = eidx + N_EDGES;         // edge_index_p[1]
    p.batch  = (const int*)d_in[5];
    p.nn0_w1 = (const float*)d_in[6];  p.nn0_b1 = (const float*)d_in[7];
    p.nn0_w2 = (const float*)d_in[8];  p.nn0_b2 = (const float*)d_in[9];
    p.nn1_w1 = (const float*)d_in[10]; p.nn1_b1 = (const float*)d_in[11];
    p.nn1_w2 = (const float*)d_in[12]; p.nn1_b2 = (const float*)d_in[13];
    p.root0  = (const float*)d_in[14]; p.bias0  = (const float*)d_in[15];
    p.root1  = (const float*)d_in[16]; p.bias1  = (const float*)d_in[17];
    p.root2  = (const float*)d_in[18]; p.bias2  = (const float*)d_in[19];
    p.lin0_w = (const float*)d_in[20]; p.lin0_b = (const float*)d_in[21];
    p.lin1_w = (const float*)d_in[22]; p.lin1_b = (const float*)d_in[23];
    p.out    = (float*)d_out;

    char* ws = (char*)d_ws;
    p.AGGa   = (float*)ws;          ws += (size_t)N_NODES * EMB * 4;
    p.AGGb   = (float*)ws;          ws += (size_t)N_NODES * EMB * 4;
    p.cnt    = (int*)ws;            ws += 2560;      // 625 ints, padded
    p.metap  = (int*)ws;            ws += (size_t)NBUCK * CAP * 4;
    p.A1p    = (float*)ws;          ws += (size_t)NBUCK * CAP * HID * 4;
    p.W2p0   = (unsigned short*)ws; ws += (size_t)NCOL * F_NODE * 2;
    p.W2p1   = (unsigned short*)ws; ws += (size_t)NCOL * EMB * 2;
    p.X0     = (float*)ws;          ws += (size_t)N_NODES * EMB * 4;
    p.X1     = (float*)ws;          ws += (size_t)N_NODES * EMB * 4;

    k_prep<<<568, 256, 0, stream>>>(p);
    k_fused<0><<<NBUCK, 512, 0, stream>>>(p);
    k_fused<1><<<NBUCK, 512, 0, stream>>>(p);
    k_fused<2><<<NBUCK, 512, 0, stream>>>(p);
    k_tail<<<NGRAPH, 512, 0, stream>>>(p);
}